// Round 8
// baseline (89.671 us; speedup 1.0000x reference)
//
#include <hip/hip_runtime.h>
#include <math.h>

#define NTX 3
#define NAX 2048
#define NEL 128
#define NPIX (512*256)

// FS / SOUND_SPEED
constexpr float DELAY_SCALE = 20000000.0f / 1540.0f;
constexpr float PITCH = 0.0003f;

typedef _Float16 half2_t __attribute__((ext_vector_type(2)));
typedef unsigned uv4 __attribute__((ext_vector_type(4)));
typedef uv4 __attribute__((aligned(4))) uv4a;  // dword-aligned 16B load
typedef unsigned short ushort_t;

// samp[t][el][ax] = (f16)data[t][ax][el]; 1.5 MB, L2-resident.
__global__ __launch_bounds__(256) void make_samp_k(const float* __restrict__ in,
                                                   _Float16* __restrict__ out) {
  __shared__ float tile[32][33];
  const int t = blockIdx.z;
  const int ax0 = blockIdx.x * 32;
  const int el0 = blockIdx.y * 32;
  const float* inp = in + (size_t)t * (NAX * NEL);
  _Float16* outp = out + (size_t)t * (NEL * NAX);
  const int lx = threadIdx.x;  // 0..31
  const int ly = threadIdx.y;  // 0..7
#pragma unroll
  for (int i = 0; i < 32; i += 8)
    tile[ly + i][lx] = inp[(size_t)(ax0 + ly + i) * NEL + (el0 + lx)];
  __syncthreads();
#pragma unroll
  for (int i = 0; i < 32; i += 8)
    outp[(size_t)(el0 + ly + i) * NAX + (ax0 + lx)] = (_Float16)tile[lx][ly + i];
}

struct LaneCtx {
  float px, z20, z21, hap0, hap1;
  float wtx0[NTX], wtx1[NTX];
};

// One lane handles 2 consecutive-z pixels; one 16B window load per (el,t)
// serves both lerps. Extraction: window s[b..b+7]; pixel needs (s[i0],s[i0+1]).
template <int B>
__device__ __forceinline__ void das_batch(int el, const _Float16* __restrict__ samp,
                                          const LaneCtx& c, float& a0, float& a1) {
  uv4 d[B][NTX];
  float f10[B][NTX], f11[B][NTX];
  int odd0[B][NTX], rel1[B][NTX];
  bool act0[B], act1[B];
#pragma unroll
  for (int j = 0; j < B; ++j) {
    const int elu = __builtin_amdgcn_readfirstlane(el + j);  // wave-uniform
    const float ex = ((float)elu - 63.5f) * PITCH;           // == probe x
    const float dx = c.px - ex;
    act0[j] = fabsf(dx) <= c.hap0;  // exact ref mask, per z-row
    act1[j] = fabsf(dx) <= c.hap1;
    const float drx0 = sqrtf(fmaf(dx, dx, c.z20)) * DELAY_SCALE;
    const float drx1 = sqrtf(fmaf(dx, dx, c.z21)) * DELAY_SCALE;
#pragma unroll
    for (int t = 0; t < NTX; ++t) {
      const float w0 = drx0 + c.wtx0[t];
      const float w1 = drx1 + c.wtx1[t];  // w1 > w0, w1-w0 <= 2.50
      int i00 = (int)w0; i00 = i00 < 0 ? 0 : i00;  // == clip(floor,0,..)
      int i01 = (int)w1; i01 = i01 < 0 ? 0 : i01;  // (upper clamp: w <= ~1470)
      const int b = i00 & ~1;  // dword-aligned window start; i01+1 <= b+7
      const ushort_t* col = (const ushort_t*)samp + (((size_t)t * NEL + elu) << 11);
      d[j][t] = *(const uv4a*)(col + b);  // SGPR base + 32-bit voffset
      f10[j][t] = w0 - (float)i00;        // == w - d0f (exact)
      f11[j][t] = w1 - (float)i01;
      odd0[j][t] = i00 & 1;
      rel1[j][t] = i01 - b;               // in [0,4]
    }
  }
#pragma unroll
  for (int j = 0; j < B; ++j) {
#pragma unroll
    for (int t = 0; t < NTX; ++t) {
      const uv4 dd = d[j][t];
      unsigned pw0 = odd0[j][t] ? ((dd.x >> 16) | (dd.y << 16)) : dd.x;
      const int k1 = rel1[j][t] >> 1;     // 0..2
      const unsigned lo1 = (k1 & 2) ? dd.z : ((k1 & 1) ? dd.y : dd.x);
      const unsigned hi1 = (k1 & 2) ? dd.w : ((k1 & 1) ? dd.z : dd.y);
      unsigned pw1 = (rel1[j][t] & 1) ? ((lo1 >> 16) | (hi1 << 16)) : lo1;
      pw0 = act0[j] ? pw0 : 0u;  // masked lanes contribute exact 0
      pw1 = act1[j] ? pw1 : 0u;
      const half2_t wh0 = __builtin_bit_cast(
          half2_t, __builtin_amdgcn_cvt_pkrtz(1.0f - f10[j][t], f10[j][t]));
      const half2_t wh1 = __builtin_bit_cast(
          half2_t, __builtin_amdgcn_cvt_pkrtz(1.0f - f11[j][t], f11[j][t]));
      a0 = __builtin_amdgcn_fdot2(wh0, __builtin_bit_cast(half2_t, pw0), a0, false);
      a1 = __builtin_amdgcn_fdot2(wh1, __builtin_bit_cast(half2_t, pw1), a1, false);
    }
  }
}

// Block: 8 waves on one 16x * 8z tile (2 z per lane), el-range split 8 ways.
__global__ __launch_bounds__(512, 4) void das_wz_k(const _Float16* __restrict__ samp,
                                                   const float* __restrict__ grid,
                                                   const float* __restrict__ probe,
                                                   const float* __restrict__ angles,
                                                   float* __restrict__ out) {
  __shared__ float2 s_part[512];
  const int tid = threadIdx.x;
  const int lane = tid & 63;
  const int wv = tid >> 6;  // 0..7
  const int x = (blockIdx.x & 15) * 16 + (lane & 15);
  const int z0 = (blockIdx.x >> 4) * 8 + (lane >> 4) * 2;
  const int pix0 = z0 * 256 + x;
  const int pix1 = pix0 + 256;

  LaneCtx c;
  c.px = grid[3 * pix0 + 0];
  const float pz0 = grid[3 * pix0 + 2];
  const float pz1 = grid[3 * pix1 + 2];
  c.z20 = pz0 * pz0;
  c.z21 = pz1 * pz1;
  c.hap0 = pz0 * 0.5f;  // (z/F#)/2, F# = 1 (exact vs ref)
  c.hap1 = pz1 * 0.5f;
#pragma unroll
  for (int t = 0; t < NTX; ++t) {
    const float a = angles[t];
    const float s = sinf(a), co = cosf(a);
    c.wtx0[t] = (c.px * s + pz0 * co) * DELAY_SCALE;
    c.wtx1[t] = (c.px * s + pz1 * co) * DELAY_SCALE;
  }

  // Conservative active-el range (union via monotonicity): lo min at
  // (x min, z max) = lane 48 (using deeper row's aperture), hi at lane 63.
  const float inv_pitch = 1.0f / PITCH;
  const int el_lo = (int)floorf((c.px - c.hap1) * inv_pitch + 63.5f) - 1;
  const int el_hi = (int)ceilf((c.px + c.hap1) * inv_pitch + 63.5f) + 1;
  int lo = __shfl(el_lo, 48);
  int hi = __shfl(el_hi, 63);
  lo = lo < 0 ? 0 : lo;
  hi = hi > NEL - 1 ? NEL - 1 : hi;

  // Split the range across the block's 8 waves.
  const int q = (hi - lo + 8) >> 3;
  const int e0 = lo + wv * q;
  int e1 = e0 + q - 1;
  e1 = e1 > hi ? hi : e1;

  float a0 = 0.0f, a1 = 0.0f;
  int el = e0;
  for (; el + 1 <= e1; el += 2) das_batch<2>(el, samp, c, a0, a1);
  for (; el <= e1; ++el) das_batch<1>(el, samp, c, a0, a1);

  s_part[tid] = make_float2(a0, a1);
  __syncthreads();
  if (tid < 64) {
    float s0 = 0.0f, s1 = 0.0f;
#pragma unroll
    for (int k = 0; k < 8; ++k) {
      const float2 p = s_part[tid + 64 * k];
      s0 += p.x;
      s1 += p.y;
    }
    out[pix0] = s0;
    out[pix1] = s1;
  }
}

// Fallback (no workspace): original layout, two scalar loads, fp32.
__global__ __launch_bounds__(256) void das_fb_k(const float* __restrict__ data,
                                                const float* __restrict__ grid,
                                                const float* __restrict__ probe,
                                                const float* __restrict__ angles,
                                                float* __restrict__ out) {
  __shared__ float s_ex[NEL];
  __shared__ float s_part[256];
  const int tid = threadIdx.x;
  if (tid < NEL) s_ex[tid] = probe[3 * tid];
  __syncthreads();
  const int pix = blockIdx.x * 64 + (tid & 63);
  const int chunk = tid >> 6;
  const float px = grid[3 * pix + 0];
  const float pz = grid[3 * pix + 2];
  const float z2 = pz * pz;
  const float half_ap = pz * 0.5f;
  float wtx[NTX];
#pragma unroll
  for (int t = 0; t < NTX; ++t) {
    const float a = angles[t];
    wtx[t] = (px * sinf(a) + pz * cosf(a)) * DELAY_SCALE;
  }
  float acc = 0.0f;
  const int el_begin = chunk * 32;
  for (int e = 0; e < 32; ++e) {
    const int el = el_begin + e;
    const float ex = s_ex[el];
    const float dx = px - ex;
    if (fabsf(dx) > half_ap) continue;
    const float base = sqrtf(fmaf(dx, dx, z2)) * DELAY_SCALE;
#pragma unroll
    for (int t = 0; t < NTX; ++t) {
      const float w = base + wtx[t];
      int i0 = (int)w;
      i0 = i0 < 0 ? 0 : i0;
      const float* colp = data + (size_t)t * (NAX * NEL) + el;
      const float s0 = colp[(size_t)i0 * NEL];
      const float s1 = colp[(size_t)(i0 + 1) * NEL];
      const float f1 = w - (float)i0;
      acc = fmaf(1.0f - f1, s0, fmaf(f1, s1, acc));
    }
  }
  s_part[tid] = acc;
  __syncthreads();
  if (tid < 64) {
    out[pix] = s_part[tid] + s_part[tid + 64] + s_part[tid + 128] + s_part[tid + 192];
  }
}

extern "C" void kernel_launch(void* const* d_in, const int* in_sizes, int n_in,
                              void* d_out, int out_size, void* d_ws, size_t ws_size,
                              hipStream_t stream) {
  const float* data = (const float*)d_in[0];    // (1, 3, 2048, 128, 1)
  const float* grid = (const float*)d_in[1];    // (131072, 3)
  const float* probe = (const float*)d_in[2];   // (128, 3)
  const float* angles = (const float*)d_in[3];  // (3,)
  float* out = (float*)d_out;                   // (1, 512, 256)

  const size_t sbytes = (size_t)NTX * NEL * NAX * sizeof(_Float16);  // 1.5 MB
  if (ws_size >= sbytes) {
    _Float16* samp = (_Float16*)d_ws;
    dim3 tb(32, 8);
    dim3 tg(NAX / 32, NEL / 32, NTX);
    make_samp_k<<<tg, tb, 0, stream>>>(data, samp);
    das_wz_k<<<1024, 512, 0, stream>>>(samp, grid, probe, angles, out);
  } else {
    das_fb_k<<<NPIX / 64, 256, 0, stream>>>(data, grid, probe, angles, out);
  }
}